// Round 4
// baseline (313.403 us; speedup 1.0000x reference)
//
#include <hip/hip_runtime.h>
#include <hip/hip_bf16.h>
#include <stdint.h>

// EdgeDecoder: out = relu(concat(zd[row], zt[col]) @ W1 + b1) @ W2 + b2
// R6: kill the ~100us prep pass. Main kernel gathers A fragments DIRECTLY
// from the ORIGINAL fp32 zd/zt (2x dwordx4 per fragment) and converts
// fp32->bf16 in-register (f2bf RNE, bit-identical to the old prep cvt).
// Prep is now only the 32-block W1 transpose (~3us, 256KB workspace).
// Main-loop structure is exactly R5 (best so far, 163us): wave owns 32
// edges x 256 cols, B via gl2lds+XOR-swizzle dbuf LDS, one vmcnt(0)+barrier
// per chunk after compute, A prefetched one full chunk ahead.

typedef unsigned short u16;
typedef __attribute__((ext_vector_type(8))) short short8;
typedef __attribute__((ext_vector_type(4))) float f32x4;

#define HDIM 256
#define KDIM 512
#define BM 128     // edges per block (4 waves x 32 edges)
#define BK 64      // k-chunk

__device__ __forceinline__ u16 f2bf(float f) {
  union { float f; uint32_t u; } v; v.f = f;
  uint32_t u = v.u;
  return (u16)((u + 0x7fffu + ((u >> 16) & 1u)) >> 16);   // RNE, inputs finite
}

// async global->LDS, 16B per lane; LDS dest must be wave-uniform base (+lane*16)
__device__ __forceinline__ void gl2lds16(const void* g, void* l) {
  __builtin_amdgcn_global_load_lds(
      (const __attribute__((address_space(1))) unsigned int*)g,
      (__attribute__((address_space(3))) unsigned int*)l,
      16, 0, 0);
}

// Prep: ONLY the 64x64 LDS-tiled transpose of W1 (512x256 fp32 -> 256x512
// bf16), coalesced both sides. 32 blocks.
__global__ void prep_kernel(const float* __restrict__ w1,
                            u16* __restrict__ w1t) {
  const int b = blockIdx.x;
  __shared__ float tile[64][65];
  const int k0 = (b >> 2) * 64, n0 = (b & 3) * 64;
  const int tx = threadIdx.x & 63, ty = threadIdx.x >> 6;
#pragma unroll
  for (int i = ty; i < 64; i += 4)
    tile[i][tx] = w1[(size_t)(k0 + i) * HDIM + n0 + tx];   // coalesced 256B
  __syncthreads();
#pragma unroll
  for (int i = ty; i < 64; i += 4)
    w1t[(size_t)(n0 + i) * KDIM + k0 + tx] = f2bf(tile[tx][i]);  // coalesced
}

// Main fused kernel. Block = 256 thr (4 waves). Wave w owns edges
// [e0 + w*32, +32) x ALL 256 cols: acc[2][16] 16x16 frags. K-loop: 8 chunks
// of BK=64 (0-3 zd[row], 4-7 zt[col]). Per chunk: stage B(kc+1) via gl2lds,
// issue A(kc+1) fp32 fragment loads, compute 64 MFMA from bf16 aB regs +
// lB ds_reads, vmcnt(0) (loads landed under compute), cvt A fp32->bf16,
// barrier.
__global__ __launch_bounds__(256, 2) void edge_mlp_kernel(
    const float* __restrict__ zdf, const float* __restrict__ ztf,
    const int* __restrict__ row, const int* __restrict__ col,
    const u16* __restrict__ w1t, const float* __restrict__ b1,
    const float* __restrict__ w2, const float* __restrict__ b2,
    float* __restrict__ out, int E) {
  __shared__ u16 lB[2][HDIM * BK];   // 2 x 32KB [n][k], 16B-slot XOR-swizzled

  const int tid   = threadIdx.x;
  const int wid   = tid >> 6;                      // 0..3
  const int lane  = tid & 63;
  const int e0    = blockIdx.x * BM;
  const int r8    = lane >> 3;                     // row-in-8-group per issue
  const int slog  = ((lane & 7) ^ (r8 & 7)) * 8;   // swizzled 16B-slot offset
  const int colid = lane & 15;
  const int quad  = lane >> 4;
  const int csw   = colid & 7;     // read-side swizzle key (row&7 == colid&7)

  // B-staging: wave w stages n-rows [w*64, w*64+64) in 8 issues (R2 scheme).
  const u16* pB = w1t + (uint32_t)(wid * 64 + r8) * KDIM + slog;

  // Per-lane A row offsets (fp32 element offsets): lane colid picks edge
  // rt*16+colid of this wave's 32 edges.
  uint32_t offD2[2], offT2[2];
#pragma unroll
  for (int rt = 0; rt < 2; ++rt) {
    int ge = min(e0 + wid * 32 + rt * 16 + colid, E - 1);
    offD2[rt] = (uint32_t)row[ge] * HDIM;
    offT2[rt] = (uint32_t)col[ge] * HDIM;
  }

  f32x4 acc[2][16];
#pragma unroll
  for (int i = 0; i < 2; ++i)
#pragma unroll
    for (int j = 0; j < 16; ++j) acc[i][j] = f32x4{0.f, 0.f, 0.f, 0.f};

  float4 a32[2][2][2];  // in-flight fp32 A for next chunk [rt][s][half]
  short8 aB[2][2];      // current-chunk bf16 A fragments [rt][s]

  // Issue fp32 A fragment loads for chunk kn (per lane: 8 floats = 2x float4
  // at zrow + koff + quad*8).
  auto loadA = [&](int kn) {
    const float* zb = (kn < 4) ? zdf : ztf;                 // static (unrolled)
    const uint32_t* offs = (kn < 4) ? offD2 : offT2;
    const int koffn = (kn & 3) * BK;
#pragma unroll
    for (int rt = 0; rt < 2; ++rt)
#pragma unroll
      for (int s = 0; s < 2; ++s) {
        const float* p = zb + offs[rt] + koffn + s * 32 + quad * 8;
        a32[rt][s][0] = ((const float4*)p)[0];
        a32[rt][s][1] = ((const float4*)p)[1];
      }
  };
  // Convert landed fp32 A to bf16 fragments (RNE, matches old prep bits).
  auto cvtA = [&]() {
#pragma unroll
    for (int rt = 0; rt < 2; ++rt)
#pragma unroll
      for (int s = 0; s < 2; ++s) {
        float4 lo = a32[rt][s][0], hi = a32[rt][s][1];
        short8 r;
        r[0] = (short)f2bf(lo.x); r[1] = (short)f2bf(lo.y);
        r[2] = (short)f2bf(lo.z); r[3] = (short)f2bf(lo.w);
        r[4] = (short)f2bf(hi.x); r[5] = (short)f2bf(hi.y);
        r[6] = (short)f2bf(hi.z); r[7] = (short)f2bf(hi.w);
        aB[rt][s] = r;
      }
  };

  // Prologue: stage B(0), load+convert A(0).
#pragma unroll
  for (int j = 0; j < 8; ++j)
    gl2lds16(pB + (size_t)j * 8 * KDIM, &lB[0][(wid * 64 + j * 8) * BK]);
  loadA(0);
  asm volatile("s_waitcnt vmcnt(0)" ::: "memory");
  cvtA();
  __builtin_amdgcn_s_barrier();

#pragma unroll
  for (int kc = 0; kc < 8; ++kc) {
    const int cur = kc & 1, nxt = cur ^ 1;
    if (kc < 7) {
      const int kn = kc + 1;
#pragma unroll
      for (int j = 0; j < 8; ++j)
        gl2lds16(pB + (size_t)j * 8 * KDIM + kn * BK,
                 &lB[nxt][(wid * 64 + j * 8) * BK]);
      loadA(kn);
    }
    // Compute chunk kc: aB (regs) x lB[cur] (LDS), 64 MFMA.
#pragma unroll
    for (int s = 0; s < 2; ++s) {
      const int sl = s * 4 + quad;                 // logical 16B slot
      __builtin_amdgcn_s_setprio(1);
#pragma unroll
      for (int ct = 0; ct < 16; ++ct) {
        short8 bF = *(const short8*)
            &lB[cur][(ct * 16 + colid) * BK + ((sl ^ csw) * 8)];
        acc[0][ct] = __builtin_amdgcn_mfma_f32_16x16x32_bf16(
            aB[0][s], bF, acc[0][ct], 0, 0, 0);
        acc[1][ct] = __builtin_amdgcn_mfma_f32_16x16x32_bf16(
            aB[1][s], bF, acc[1][ct], 0, 0, 0);
      }
      __builtin_amdgcn_s_setprio(0);
    }
    if (kc < 7) {
      // Drain next-chunk stages/loads (covered by compute), cvt, barrier.
      asm volatile("s_waitcnt vmcnt(0)" ::: "memory");
      cvtA();
      __builtin_amdgcn_s_barrier();
    }
  }

  // Epilogue (wave-local, no LDS): h = relu(acc + b1[n]); out = h @ W2 + b2.
  // C/D layout: n = ct*16 + colid, e = wid*32 + rt*16 + quad*4 + j.
  float b1v[16], w2v[16];
#pragma unroll
  for (int ct = 0; ct < 16; ++ct) {
    b1v[ct] = b1[ct * 16 + colid];
    w2v[ct] = w2[ct * 16 + colid];
  }
  const float b2v = b2[0];
#pragma unroll
  for (int rt = 0; rt < 2; ++rt)
#pragma unroll
    for (int j = 0; j < 4; ++j) {
      float s = 0.f;
#pragma unroll
      for (int ct = 0; ct < 16; ++ct)
        s += fmaxf(acc[rt][ct][j] + b1v[ct], 0.f) * w2v[ct];
#pragma unroll
      for (int off = 8; off >= 1; off >>= 1)
        s += __shfl_xor(s, off, 16);               // sum over the 16 colids
      if (colid == 0) {
        int ge = e0 + wid * 32 + rt * 16 + quad * 4 + j;
        if (ge < E) out[ge] = s + b2v;
      }
    }
}

// Correct-but-slow fp32 fallback (only if ws_size < 256KB): 16 edges/block.
__global__ void fallback_kernel(
    const float* __restrict__ zd, const float* __restrict__ zt,
    const int* __restrict__ row, const int* __restrict__ col,
    const float* __restrict__ W1, const float* __restrict__ b1,
    const float* __restrict__ W2, const float* __restrict__ b2,
    float* __restrict__ out, int E) {
  __shared__ float zc[16][512];
  __shared__ float red[4][16];
  const int e0 = blockIdx.x * 16;
  const int tid = threadIdx.x;
  for (int i = tid; i < 16 * 512; i += 256) {
    int e = i >> 9, k = i & 511;
    int ge = min(e0 + e, E - 1);
    zc[e][k] = (k < HDIM) ? zd[(size_t)row[ge] * HDIM + k]
                          : zt[(size_t)col[ge] * HDIM + (k - HDIM)];
  }
  __syncthreads();
  float acc[16];
#pragma unroll
  for (int e = 0; e < 16; ++e) acc[e] = 0.f;
  for (int k = 0; k < KDIM; ++k) {
    float w = W1[k * HDIM + tid];
#pragma unroll
    for (int e = 0; e < 16; ++e) acc[e] += zc[e][k] * w;
  }
  float wv = W2[tid], bv = b1[tid];
  const int lane = tid & 63, wid = tid >> 6;
#pragma unroll
  for (int e = 0; e < 16; ++e) {
    float pv = fmaxf(acc[e] + bv, 0.f) * wv;
#pragma unroll
    for (int off = 32; off >= 1; off >>= 1) pv += __shfl_down(pv, off, 64);
    if (lane == 0) red[wid][e] = pv;
  }
  __syncthreads();
  if (tid < 16) {
    int ge = e0 + tid;
    if (ge < E)
      out[ge] = red[0][tid] + red[1][tid] + red[2][tid] + red[3][tid] + b2[0];
  }
}

extern "C" void kernel_launch(void* const* d_in, const int* in_sizes, int n_in,
                              void* d_out, int out_size, void* d_ws, size_t ws_size,
                              hipStream_t stream) {
  const float* zd_f = (const float*)d_in[0];
  const float* zt_f = (const float*)d_in[1];
  const int*   row  = (const int*)d_in[2];
  const int*   col  = (const int*)d_in[3];
  const float* W1   = (const float*)d_in[4];
  const float* b1   = (const float*)d_in[5];
  const float* W2   = (const float*)d_in[6];
  const float* b2   = (const float*)d_in[7];
  float* out = (float*)d_out;

  const int E = in_sizes[2];             // 500000

  size_t need = (size_t)KDIM * HDIM * sizeof(u16);   // 256KB for W1T

  if (ws_size >= need) {
    u16* w1t = (u16*)d_ws;
    prep_kernel<<<32, 256, 0, stream>>>(W1, w1t);
    edge_mlp_kernel<<<(E + BM - 1) / BM, 256, 0, stream>>>(
        zd_f, zt_f, row, col, w1t, b1, W2, b2, out, E);
  } else {
    fallback_kernel<<<(E + 15) / 16, 256, 0, stream>>>(
        zd_f, zt_f, row, col, W1, b1, W2, b2, out, E);
  }
}

// Round 5
// 260.822 us; speedup vs baseline: 1.2016x; 1.2016x over previous
//
#include <hip/hip_runtime.h>
#include <hip/hip_bf16.h>
#include <stdint.h>

// EdgeDecoder: out = relu(concat(zd[row], zt[col]) @ W1 + b1) @ W2 + b2
// R7 = R5 (best kernel, 163us: bf16 z via prep, wave owns 32 edges x 256
// cols, B via gl2lds+XOR-swizzle dbuf LDS, A direct global->VGPR prefetched
// one chunk ahead) + ONE change: counted vmcnt(4) drain. Per chunk the 8
// B-stage gl2lds are issued FIRST (oldest), sched_barrier(0) pins order,
// then the 4 A-gathers (youngest). The pre-barrier drain waits vmcnt(4):
// stages complete (cross-wave LDS contract holds), A-gathers keep flying
// across the barrier; their wait is the compiler's counted wait at first
// MFMA use next chunk (a full compute phase of latency hiding, no barrier
// amplification of gather tails). R6 lesson: gather path is byte-bound ->
// bf16 z restored; fp32 conversion prep (~25us) is worth it.

typedef unsigned short u16;
typedef __attribute__((ext_vector_type(8))) short short8;
typedef __attribute__((ext_vector_type(4))) float f32x4;

#define HDIM 256
#define KDIM 512
#define BM 128     // edges per block (4 waves x 32 edges)
#define BK 64      // k-chunk

__device__ __forceinline__ u16 f2bf(float f) {
  union { float f; uint32_t u; } v; v.f = f;
  uint32_t u = v.u;
  return (u16)((u + 0x7fffu + ((u >> 16) & 1u)) >> 16);   // RNE, inputs finite
}

// async global->LDS, 16B per lane; LDS dest must be wave-uniform base (+lane*16)
__device__ __forceinline__ void gl2lds16(const void* g, void* l) {
  __builtin_amdgcn_global_load_lds(
      (const __attribute__((address_space(1))) unsigned int*)g,
      (__attribute__((address_space(3))) unsigned int*)l,
      16, 0, 0);
}

// One prep kernel: blocks 0..31 do a 64x64 LDS-tiled transpose of W1
// (512x256 fp32 -> W1T 256x512 bf16, coalesced both sides); remaining blocks
// grid-stride-convert zd then zt to bf16 via float4 loads.
#define CVT_BLOCKS 4096
__global__ void prep_kernel(const float* __restrict__ zd_f,
                            const float* __restrict__ zt_f,
                            const float* __restrict__ w1,
                            u16* __restrict__ zdb, u16* __restrict__ ztb,
                            u16* __restrict__ w1t, int n4d, int n4t) {
  const int b = blockIdx.x;
  if (b < 32) {
    __shared__ float tile[64][65];
    const int k0 = (b >> 2) * 64, n0 = (b & 3) * 64;
    const int tx = threadIdx.x & 63, ty = threadIdx.x >> 6;
#pragma unroll
    for (int i = ty; i < 64; i += 4)
      tile[i][tx] = w1[(size_t)(k0 + i) * HDIM + n0 + tx];   // coalesced 256B
    __syncthreads();
#pragma unroll
    for (int i = ty; i < 64; i += 4)
      w1t[(size_t)(n0 + i) * KDIM + k0 + tx] = f2bf(tile[tx][i]);  // coalesced
  } else {
    const int idx = (b - 32) * 256 + threadIdx.x;
    const int stride = CVT_BLOCKS * 256;
    for (int i = idx; i < n4d; i += stride) {
      float4 v = ((const float4*)zd_f)[i];
      ushort4 o; o.x = f2bf(v.x); o.y = f2bf(v.y); o.z = f2bf(v.z); o.w = f2bf(v.w);
      ((ushort4*)zdb)[i] = o;
    }
    for (int i = idx; i < n4t; i += stride) {
      float4 v = ((const float4*)zt_f)[i];
      ushort4 o; o.x = f2bf(v.x); o.y = f2bf(v.y); o.z = f2bf(v.z); o.w = f2bf(v.w);
      ((ushort4*)ztb)[i] = o;
    }
  }
}

// Main fused kernel. Block = 256 thr (4 waves). Wave w owns edges
// [e0 + w*32, +32) x ALL 256 cols: acc[2][16] 16x16 frags. K-loop: 8 chunks
// of BK=64 (0-3 zd[row], 4-7 zt[col]). Per chunk: stage B(kc+1) via gl2lds
// (oldest 8 vmem), sched_barrier pin, A(kc+1) per-lane fragment loads
// (youngest 4), 64 MFMA from aR regs + lB ds_reads, then vmcnt(4)+barrier:
// stages guaranteed, A-gathers fly across the barrier.
__global__ __launch_bounds__(256, 2) void edge_mlp_kernel(
    const u16* __restrict__ zd, const u16* __restrict__ zt,
    const int* __restrict__ row, const int* __restrict__ col,
    const u16* __restrict__ w1t, const float* __restrict__ b1,
    const float* __restrict__ w2, const float* __restrict__ b2,
    float* __restrict__ out, int E) {
  __shared__ u16 lB[2][HDIM * BK];   // 2 x 32KB [n][k], 16B-slot XOR-swizzled

  const int tid   = threadIdx.x;
  const int wid   = tid >> 6;                      // 0..3
  const int lane  = tid & 63;
  const int e0    = blockIdx.x * BM;
  const int r8    = lane >> 3;                     // row-in-8-group per issue
  const int slog  = ((lane & 7) ^ (r8 & 7)) * 8;   // swizzled 16B-slot offset
  const int colid = lane & 15;
  const int quad  = lane >> 4;
  const int csw   = colid & 7;     // read-side swizzle key (row&7 == colid&7)

  // B-staging: wave w stages n-rows [w*64, w*64+64) in 8 issues (R2 scheme).
  const u16* pB = w1t + (uint32_t)(wid * 64 + r8) * KDIM + slog;

  // Per-lane A row offsets: lane colid picks edge rt*16+colid of this wave.
  uint32_t offD2[2], offT2[2];
#pragma unroll
  for (int rt = 0; rt < 2; ++rt) {
    int ge = min(e0 + wid * 32 + rt * 16 + colid, E - 1);
    offD2[rt] = (uint32_t)row[ge] * HDIM;
    offT2[rt] = (uint32_t)col[ge] * HDIM;
  }

  f32x4 acc[2][16];
#pragma unroll
  for (int i = 0; i < 2; ++i)
#pragma unroll
    for (int j = 0; j < 16; ++j) acc[i][j] = f32x4{0.f, 0.f, 0.f, 0.f};

  short8 aR[2][2][2];   // [kc&1][rt][s] — static-indexed (K-loop fully unrolled)

  // Prologue: stage B(0) (oldest), pin, load A(0) (youngest), counted drain.
#pragma unroll
  for (int j = 0; j < 8; ++j)
    gl2lds16(pB + (size_t)j * 8 * KDIM, &lB[0][(wid * 64 + j * 8) * BK]);
  __builtin_amdgcn_sched_barrier(0);
#pragma unroll
  for (int rt = 0; rt < 2; ++rt)
#pragma unroll
    for (int s = 0; s < 2; ++s)
      aR[0][rt][s] = *(const short8*)(zd + offD2[rt] + s * 32 + quad * 8);
  asm volatile("s_waitcnt vmcnt(4)" ::: "memory");  // 8 stages done; A flies
  __builtin_amdgcn_s_barrier();

#pragma unroll
  for (int kc = 0; kc < 8; ++kc) {
    const int cur = kc & 1, nxt = cur ^ 1;
    if (kc < 7) {
      const int kn = kc + 1;
      // Stages first (oldest 8 vmem this chunk)...
#pragma unroll
      for (int j = 0; j < 8; ++j)
        gl2lds16(pB + (size_t)j * 8 * KDIM + kn * BK,
                 &lB[nxt][(wid * 64 + j * 8) * BK]);
      __builtin_amdgcn_sched_barrier(0);   // pin: no A-load above this line
      // ...then A-gathers (youngest 4; may cross the barrier in flight).
      const u16* zb = (kn < 4) ? zd : zt;                     // static
      const uint32_t* offs = (kn < 4) ? offD2 : offT2;        // static
      const int koffn = (kn & 3) * BK;
#pragma unroll
      for (int rt = 0; rt < 2; ++rt)
#pragma unroll
        for (int s = 0; s < 2; ++s)
          aR[nxt][rt][s] =
              *(const short8*)(zb + offs[rt] + koffn + s * 32 + quad * 8);
    }
    // Compute chunk kc: aR[cur] (regs) x lB[cur] (LDS), 64 MFMA.
#pragma unroll
    for (int s = 0; s < 2; ++s) {
      const int sl = s * 4 + quad;                 // logical 16B slot
      __builtin_amdgcn_s_setprio(1);
#pragma unroll
      for (int ct = 0; ct < 16; ++ct) {
        short8 bF = *(const short8*)
            &lB[cur][(ct * 16 + colid) * BK + ((sl ^ csw) * 8)];
        acc[0][ct] = __builtin_amdgcn_mfma_f32_16x16x32_bf16(
            aR[cur][0][s], bF, acc[0][ct], 0, 0, 0);
        acc[1][ct] = __builtin_amdgcn_mfma_f32_16x16x32_bf16(
            aR[cur][1][s], bF, acc[1][ct], 0, 0, 0);
      }
      __builtin_amdgcn_s_setprio(0);
    }
    if (kc < 7) {
      // Counted drain: the 8 stage ops (oldest) complete; the 4 A-gathers
      // (youngest) stay in flight across the barrier — their wait is the
      // compiler's counted vmcnt before first aR use next chunk.
      asm volatile("s_waitcnt vmcnt(4)" ::: "memory");
      __builtin_amdgcn_s_barrier();
    }
  }

  // Epilogue (wave-local, no LDS): h = relu(acc + b1[n]); out = h @ W2 + b2.
  // C/D layout: n = ct*16 + colid, e = wid*32 + rt*16 + quad*4 + j.
  float b1v[16], w2v[16];
#pragma unroll
  for (int ct = 0; ct < 16; ++ct) {
    b1v[ct] = b1[ct * 16 + colid];
    w2v[ct] = w2[ct * 16 + colid];
  }
  const float b2v = b2[0];
#pragma unroll
  for (int rt = 0; rt < 2; ++rt)
#pragma unroll
    for (int j = 0; j < 4; ++j) {
      float s = 0.f;
#pragma unroll
      for (int ct = 0; ct < 16; ++ct)
        s += fmaxf(acc[rt][ct][j] + b1v[ct], 0.f) * w2v[ct];
#pragma unroll
      for (int off = 8; off >= 1; off >>= 1)
        s += __shfl_xor(s, off, 16);               // sum over the 16 colids
      if (colid == 0) {
        int ge = e0 + wid * 32 + rt * 16 + quad * 4 + j;
        if (ge < E) out[ge] = s + b2v;
      }
    }
}

// Correct-but-slow fp32 fallback (only if ws_size < 36.2MB): 16 edges/block.
__global__ void fallback_kernel(
    const float* __restrict__ zd, const float* __restrict__ zt,
    const int* __restrict__ row, const int* __restrict__ col,
    const float* __restrict__ W1, const float* __restrict__ b1,
    const float* __restrict__ W2, const float* __restrict__ b2,
    float* __restrict__ out, int E) {
  __shared__ float zc[16][512];
  __shared__ float red[4][16];
  const int e0 = blockIdx.x * 16;
  const int tid = threadIdx.x;
  for (int i = tid; i < 16 * 512; i += 256) {
    int e = i >> 9, k = i & 511;
    int ge = min(e0 + e, E - 1);
    zc[e][k] = (k < HDIM) ? zd[(size_t)row[ge] * HDIM + k]
                          : zt[(size_t)col[ge] * HDIM + (k - HDIM)];
  }
  __syncthreads();
  float acc[16];
#pragma unroll
  for (int e = 0; e < 16; ++e) acc[e] = 0.f;
  for (int k = 0; k < KDIM; ++k) {
    float w = W1[k * HDIM + tid];
#pragma unroll
    for (int e = 0; e < 16; ++e) acc[e] += zc[e][k] * w;
  }
  float wv = W2[tid], bv = b1[tid];
  const int lane = tid & 63, wid = tid >> 6;
#pragma unroll
  for (int e = 0; e < 16; ++e) {
    float pv = fmaxf(acc[e] + bv, 0.f) * wv;
#pragma unroll
    for (int off = 32; off >= 1; off >>= 1) pv += __shfl_down(pv, off, 64);
    if (lane == 0) red[wid][e] = pv;
  }
  __syncthreads();
  if (tid < 16) {
    int ge = e0 + tid;
    if (ge < E)
      out[ge] = red[0][tid] + red[1][tid] + red[2][tid] + red[3][tid] + b2[0];
  }
}

extern "C" void kernel_launch(void* const* d_in, const int* in_sizes, int n_in,
                              void* d_out, int out_size, void* d_ws, size_t ws_size,
                              hipStream_t stream) {
  const float* zd_f = (const float*)d_in[0];
  const float* zt_f = (const float*)d_in[1];
  const int*   row  = (const int*)d_in[2];
  const int*   col  = (const int*)d_in[3];
  const float* W1   = (const float*)d_in[4];
  const float* b1   = (const float*)d_in[5];
  const float* W2   = (const float*)d_in[6];
  const float* b2   = (const float*)d_in[7];
  float* out = (float*)d_out;

  const int E  = in_sizes[2];            // 500000
  const int ND = in_sizes[0] / HDIM;     // 50000
  const int NT = in_sizes[1] / HDIM;     // 20000

  size_t off_w1t = 0;                                    // 256KB
  size_t off_zd  = (size_t)KDIM * HDIM * sizeof(u16);
  size_t off_zt  = off_zd + (size_t)ND * HDIM * sizeof(u16);
  size_t need    = off_zt + (size_t)NT * HDIM * sizeof(u16);  // ~36.1MB

  if (ws_size >= need) {
    u16* w1t = (u16*)((char*)d_ws + off_w1t);
    u16* zdb = (u16*)((char*)d_ws + off_zd);
    u16* ztb = (u16*)((char*)d_ws + off_zt);
    int n4d = ND * HDIM / 4, n4t = NT * HDIM / 4;
    prep_kernel<<<32 + CVT_BLOCKS, 256, 0, stream>>>(zd_f, zt_f, W1,
                                                     zdb, ztb, w1t, n4d, n4t);
    edge_mlp_kernel<<<(E + BM - 1) / BM, 256, 0, stream>>>(
        zdb, ztb, row, col, w1t, b1, W2, b2, out, E);
  } else {
    fallback_kernel<<<(E + 15) / 16, 256, 0, stream>>>(
        zd_f, zt_f, row, col, W1, b1, W2, b2, out, E);
  }
}